// Round 2
// baseline (1100.604 us; speedup 1.0000x reference)
//
#include <hip/hip_runtime.h>
#include <math.h>

constexpr int cB = 8, cT = 2048, cDU = 512, cDM = 512, cDA = 256, cDF = 12, cL = 4;
constexpr float cEPS = 1e-6f;
constexpr float cSCALE = 16.0f;   // sqrt(DA)
constexpr float cGAMMA = 1.0f;

typedef unsigned short u16;
typedef u16 u16x8 __attribute__((ext_vector_type(8)));

// ---------------- workspace layout ----------------
// float region (element offsets)
constexpr size_t F_SB = 0;                 // sbias  B*T
constexpr size_t F_UN = F_SB + 16384;      // unorm2 B*T
constexpr size_t F_LG = F_UN + 16384;      // logits B*T
constexpr size_t F_Y  = F_LG + 16384;      // y      B*T
constexpr size_t F_PR = F_Y  + 16384;      // prev   B*T
constexpr size_t F_OV = F_PR + 16384;      // overlap B*T
constexpr size_t F_Q  = F_OV + 16384;      // q   B*DA
constexpr size_t F_QK = F_Q  + 2048;       // qk  B*DU
constexpr size_t F_M0 = F_QK + 4096;       // memory buf 0
constexpr size_t F_M1 = F_M0 + 4096;       // memory buf 1
constexpr size_t F_C  = F_M1 + 4096;       // c_raw B*DU
constexpr size_t F_CN = F_C  + 4096;       // cnorm B*DU
constexpr size_t F_Z  = F_CN + 4096;       // z B*DU
constexpr size_t F_SC = F_Z  + 4096;       // scalars B*8
constexpr size_t F_END = F_SC + 64;        // 124992 floats
// byte offsets for bf16 regions (16B aligned)
constexpr size_t U_OFFB   = F_END * 4;                       // 499968
constexpr size_t U_BYTES  = (size_t)cB * cT * cDU * 2;       // 16777216
constexpr size_t SIM_OFFB = U_OFFB + U_BYTES;                // 17277184
constexpr size_t SIM_BYTES= (size_t)cB * cT * cT * 2;        // 67108864
constexpr size_t WS_NEED_U   = U_OFFB + U_BYTES;
constexpr size_t WS_NEED_ALL = SIM_OFFB + SIM_BYTES;
// scal: 0 ysum_clamped, 1 coverage, 2 entropy, 3 wsq, 4 spread_rawsum, 6 csq, 7 cen2

__device__ __forceinline__ float wave_sum(float v) {
#pragma unroll
  for (int o = 32; o; o >>= 1) v += __shfl_down(v, o);
  return v;
}
__device__ __forceinline__ float block_reduce_sum(float v, float* red) {
  int tid = threadIdx.x;
  red[tid] = v; __syncthreads();
  for (int s = 512; s; s >>= 1) { if (tid < s) red[tid] += red[tid + s]; __syncthreads(); }
  float r = red[0]; __syncthreads();
  return r;
}
__device__ __forceinline__ float block_reduce_max(float v, float* red) {
  int tid = threadIdx.x;
  red[tid] = v; __syncthreads();
  for (int s = 512; s; s >>= 1) { if (tid < s) red[tid] = fmaxf(red[tid], red[tid + s]); __syncthreads(); }
  float r = red[0]; __syncthreads();
  return r;
}
__device__ __forceinline__ u16 f2bf(float f) {
  unsigned u = __float_as_uint(f);
  unsigned r = (u + 0x7fffu + ((u >> 16) & 1u)) >> 16;
  return (u16)r;
}
__device__ __forceinline__ float bf2f(u16 h) { return __uint_as_float(((unsigned)h) << 16); }
__device__ __forceinline__ float dot4(float4 a, float4 b) {
  return a.x * b.x + a.y * b.y + a.z * b.z + a.w * b.w;
}

// ---------------- cast u (+ sim) to bf16 ----------------
__global__ void k_cast(const float* __restrict__ u, const float* __restrict__ sim,
                       u16* __restrict__ ubf, u16* __restrict__ simbf, int do_sim) {
  const int NU8 = (cB * cT * cDU) / 8;       // 1048576
  const int NS8 = (cB * cT * cT) / 8;        // 4194304
  int total = do_sim ? (NU8 + NS8) : NU8;
  for (int idx = blockIdx.x * blockDim.x + threadIdx.x; idx < total;
       idx += gridDim.x * blockDim.x) {
    const float4* src; u16* dst; size_t c;
    if (idx < NU8) { src = (const float4*)u; dst = ubf; c = idx; }
    else           { src = (const float4*)sim; dst = simbf; c = idx - NU8; }
    float4 f0 = src[c * 2], f1 = src[c * 2 + 1];
    u16x8 o;
    o[0] = f2bf(f0.x); o[1] = f2bf(f0.y); o[2] = f2bf(f0.z); o[3] = f2bf(f0.w);
    o[4] = f2bf(f1.x); o[5] = f2bf(f1.y); o[6] = f2bf(f1.z); o[7] = f2bf(f1.w);
    *(u16x8*)(dst + c * 8) = o;
  }
}

// ---------------- precompute: sbias + unorm2 (one wave per (b,t)) ----------------
__global__ void k_pre(const float* __restrict__ sf, const float* __restrict__ u,
                      const float* __restrict__ w1, const float* __restrict__ b1,
                      const float* __restrict__ w2, const float* __restrict__ b2,
                      float* __restrict__ sbias, float* __restrict__ unorm2) {
  int wid = (blockIdx.x * blockDim.x + threadIdx.x) >> 6;
  int lane = threadIdx.x & 63;
  float d0 = sf[(size_t)wid * cDF + 8];
  float d1 = sf[(size_t)wid * cDF + 9];
  float d2 = sf[(size_t)wid * cDF + 10];
  float acc = 0.f;
#pragma unroll
  for (int i = 0; i < 4; ++i) {
    int a = lane * 4 + i;
    float h = d0 * w1[a * 3 + 0] + d1 * w1[a * 3 + 1] + d2 * w1[a * 3 + 2] + b1[a];
    float g = 0.5f * h * (1.0f + erff(h * 0.70710678118654752f));
    acc += g * w2[a];
  }
  float un = 0.f;
  const float4* ur = (const float4*)(u + (size_t)wid * cDU);
#pragma unroll
  for (int m = 0; m < 2; ++m) {
    float4 x = ur[lane + m * 64];
    un += dot4(x, x);
  }
  acc = wave_sum(acc);
  un = wave_sum(un);
  if (lane == 0) { sbias[wid] = acc + b2[0]; unorm2[wid] = un; }
}

// ---------------- q = memory @ Wq^T (wave per (b,a)) ----------------
__global__ void k_q(const float* __restrict__ mem, const float* __restrict__ Wq,
                    float* __restrict__ q) {
  int wid = (blockIdx.x * blockDim.x + threadIdx.x) >> 6;
  int lane = threadIdx.x & 63;
  int b = wid >> 8, a = wid & 255;
  const float4* mr = (const float4*)(mem + (size_t)b * cDM);
  const float4* wr = (const float4*)(Wq + (size_t)a * cDM);
  float acc = 0.f;
#pragma unroll
  for (int m = 0; m < 2; ++m) acc += dot4(mr[lane + m * 64], wr[lane + m * 64]);
  acc = wave_sum(acc);
  if (lane == 0) q[wid] = acc;
}

// ---------------- qk = Wk^T @ q  (per b) ----------------
__global__ __launch_bounds__(512) void k_qk(const float* __restrict__ q,
                                            const float* __restrict__ Wk,
                                            float* __restrict__ qk) {
  __shared__ float qs[cDA];
  int b = blockIdx.x, j = threadIdx.x;
  if (j < cDA) qs[j] = q[b * cDA + j];
  __syncthreads();
  float acc = 0.f;
#pragma unroll 4
  for (int a = 0; a < cDA; ++a) acc += Wk[(size_t)a * cDU + j] * qs[a];
  qk[b * cDU + j] = acc;
}

// ---------------- logits = (u.qk/SCALE + sbias - gamma*sim@prev)/temp ----------------
__global__ void k_scores(const u16* __restrict__ ubf, const float* __restrict__ uf,
                         const float* __restrict__ qk, const float* __restrict__ sbias,
                         const u16* __restrict__ simbf, const float* __restrict__ simf,
                         const float* __restrict__ prev, const float* __restrict__ log_temp,
                         float gamma, int use_ubf, int use_simbf,
                         float* __restrict__ logits) {
  int wid = (blockIdx.x * blockDim.x + threadIdx.x) >> 6;
  int lane = threadIdx.x & 63;
  int b = wid >> 11;
  const float4* qk4 = (const float4*)(qk + (size_t)b * cDU);
  float4 q0 = qk4[lane * 2], q1 = qk4[lane * 2 + 1];
  float acc;
  if (use_ubf) {
    u16x8 s = *(const u16x8*)(ubf + (size_t)wid * cDU + lane * 8);
    acc = bf2f(s[0]) * q0.x + bf2f(s[1]) * q0.y + bf2f(s[2]) * q0.z + bf2f(s[3]) * q0.w +
          bf2f(s[4]) * q1.x + bf2f(s[5]) * q1.y + bf2f(s[6]) * q1.z + bf2f(s[7]) * q1.w;
  } else {
    const float4* ur = (const float4*)(uf + (size_t)wid * cDU);
    acc = dot4(ur[lane * 2], q0) + dot4(ur[lane * 2 + 1], q1);
  }
  acc *= (1.0f / cSCALE);
  if (gamma != 0.0f) {
    float sd = 0.f;
    const float4* pr4 = (const float4*)(prev + (size_t)b * cT);
    if (use_simbf) {
#pragma unroll
      for (int m = 0; m < 4; ++m) {
        u16x8 s = *(const u16x8*)(simbf + (size_t)wid * cT + m * 512 + lane * 8);
        float4 p0 = pr4[m * 128 + lane * 2], p1 = pr4[m * 128 + lane * 2 + 1];
        sd += bf2f(s[0]) * p0.x + bf2f(s[1]) * p0.y + bf2f(s[2]) * p0.z + bf2f(s[3]) * p0.w +
              bf2f(s[4]) * p1.x + bf2f(s[5]) * p1.y + bf2f(s[6]) * p1.z + bf2f(s[7]) * p1.w;
      }
    } else {
      const float4* sr = (const float4*)(simf + (size_t)wid * cT);
#pragma unroll
      for (int m = 0; m < 8; ++m) sd += dot4(sr[lane + m * 64], pr4[lane + m * 64]);
    }
    acc -= gamma * sd;
  }
  acc = wave_sum(acc);
  if (lane == 0) {
    float temp = fminf(fmaxf(expf(log_temp[0]), 0.1f), 10.0f);
    logits[wid] = (acc + sbias[wid]) / temp;
  }
}

// ---------------- softmax over T per b ----------------
__global__ __launch_bounds__(1024) void k_softmax(const float* __restrict__ logits,
                                                  float* __restrict__ y) {
  __shared__ float red[1024];
  int b = blockIdx.x, tid = threadIdx.x;
  int i0 = b * cT + tid, i1 = i0 + 1024;
  float l0 = logits[i0], l1 = logits[i1];
  float m = block_reduce_max(fmaxf(l0, l1), red);
  float e0 = expf(l0 - m), e1 = expf(l1 - m);
  float S = block_reduce_sum(e0 + e1, red);
  y[i0] = e0 / S; y[i1] = e1 / S;
}

// ---------------- overlap = sim @ y ----------------
__global__ void k_overlap(const u16* __restrict__ simbf, const float* __restrict__ simf,
                          const float* __restrict__ y, int use_simbf,
                          float* __restrict__ overlap) {
  int wid = (blockIdx.x * blockDim.x + threadIdx.x) >> 6;
  int lane = threadIdx.x & 63;
  int b = wid >> 11;
  const float4* yr4 = (const float4*)(y + (size_t)b * cT);
  float acc = 0.f;
  if (use_simbf) {
#pragma unroll
    for (int m = 0; m < 4; ++m) {
      u16x8 s = *(const u16x8*)(simbf + (size_t)wid * cT + m * 512 + lane * 8);
      float4 p0 = yr4[m * 128 + lane * 2], p1 = yr4[m * 128 + lane * 2 + 1];
      acc += bf2f(s[0]) * p0.x + bf2f(s[1]) * p0.y + bf2f(s[2]) * p0.z + bf2f(s[3]) * p0.w +
             bf2f(s[4]) * p1.x + bf2f(s[5]) * p1.y + bf2f(s[6]) * p1.z + bf2f(s[7]) * p1.w;
    }
  } else {
    const float4* sr = (const float4*)(simf + (size_t)wid * cT);
#pragma unroll
    for (int m = 0; m < 8; ++m) acc += dot4(sr[lane + m * 64], yr4[lane + m * 64]);
  }
  acc = wave_sum(acc);
  if (lane == 0) overlap[wid] = acc;
}

// ---------------- penalty + softmax#2 + prev + coverage/entropy/wsq + zero accums ------
__global__ __launch_bounds__(1024) void k_soft2(const float* __restrict__ overlap,
                                                const float* __restrict__ logits,
                                                float* __restrict__ y, float* __restrict__ prev,
                                                const float* __restrict__ unorm2,
                                                float* __restrict__ scal,
                                                float* __restrict__ c_raw, int first_stage) {
  __shared__ float red[1024];
  int b = blockIdx.x, tid = threadIdx.x;
  int i0 = b * cT + tid, i1 = i0 + 1024;
  float o0 = overlap[i0], o1 = overlap[i1];
  float mo = fmaxf(block_reduce_max(fmaxf(o0, o1), red), cEPS);
  float l0 = logits[i0] - o0 / mo;
  float l1 = logits[i1] - o1 / mo;
  float ml = block_reduce_max(fmaxf(l0, l1), red);
  float e0 = expf(l0 - ml), e1 = expf(l1 - ml);
  float S = block_reduce_sum(e0 + e1, red);
  float y0 = e0 / S, y1 = e1 / S;
  y[i0] = y0; y[i1] = y1;
  if (first_stage) { prev[i0] = y0; prev[i1] = y1; }
  else             { prev[i0] += y0; prev[i1] += y1; }
  if (tid < cDU) c_raw[b * cDU + tid] = 0.f;   // zero centroid accumulator
  float ysr = block_reduce_sum(y0 + y1, red);
  float ysc = fmaxf(ysr, cEPS);
  float wsq = block_reduce_sum(y0 * unorm2[i0] + y1 * unorm2[i1], red);
  float yn0 = y0 / ysc, yn1 = y1 / ysc;
  float ent = block_reduce_sum(-yn0 * logf(fmaxf(yn0, cEPS)) - yn1 * logf(fmaxf(yn1, cEPS)), red);
  if (tid == 0) {
    scal[b * 8 + 0] = ysc;
    scal[b * 8 + 1] = ysr / (float)cT;
    scal[b * 8 + 2] = ent;
    scal[b * 8 + 3] = wsq;
    scal[b * 8 + 4] = 0.f;                     // zero spread accumulator
  }
}

// ---------------- centroid partials: c_raw += y @ u ----------------
__global__ __launch_bounds__(256) void k_cen1(const float* __restrict__ y,
                                              const u16* __restrict__ ubf,
                                              const float* __restrict__ uf, int use_ubf,
                                              float* __restrict__ c_raw) {
  int b = blockIdx.y, tc = blockIdx.x, d = threadIdx.x;
  float c0 = 0.f, c1 = 0.f;
  for (int i = 0; i < 64; ++i) {
    int row = b * cT + tc * 64 + i;
    float yv = y[row];
    if (use_ubf) {
      c0 += yv * bf2f(ubf[(size_t)row * cDU + d]);
      c1 += yv * bf2f(ubf[(size_t)row * cDU + d + 256]);
    } else {
      c0 += yv * uf[(size_t)row * cDU + d];
      c1 += yv * uf[(size_t)row * cDU + d + 256];
    }
  }
  atomicAdd(&c_raw[b * cDU + d], c0);
  atomicAdd(&c_raw[b * cDU + d + 256], c1);
}

// ---------------- fused: z = c_raw @ Wv^T  +  centroid finalize ----------------
__global__ __launch_bounds__(256) void k_zcen(const float* __restrict__ c_raw,
                                              const float* __restrict__ Wv,
                                              float* __restrict__ z,
                                              float* __restrict__ cnorm,
                                              float* __restrict__ scal) {
  if (blockIdx.x < 1024) {
    int wid = blockIdx.x * 4 + (threadIdx.x >> 6);
    int lane = threadIdx.x & 63;
    int b = wid >> 9, j = wid & 511;
    const float4* c4 = (const float4*)(c_raw + (size_t)b * cDU);
    const float4* w4 = (const float4*)(Wv + (size_t)j * cDU);
    float acc = dot4(c4[lane * 2], w4[lane * 2]) + dot4(c4[lane * 2 + 1], w4[lane * 2 + 1]);
    acc = wave_sum(acc);
    if (lane == 0) z[b * cDU + j] = acc;
  } else {
    __shared__ float red[256];
    int b = blockIdx.x - 1024, tid = threadIdx.x;
    float ysc = scal[b * 8 + 0];
    float c0 = c_raw[b * cDU + tid], c1 = c_raw[b * cDU + tid + 256];
    float n0 = c0 / ysc, n1 = c1 / ysc;
    cnorm[b * cDU + tid] = n0; cnorm[b * cDU + tid + 256] = n1;
    red[tid] = c0 * c0 + c1 * c1; __syncthreads();
    for (int s = 128; s; s >>= 1) { if (tid < s) red[tid] += red[tid + s]; __syncthreads(); }
    float csq = red[0]; __syncthreads();
    red[tid] = n0 * n0 + n1 * n1; __syncthreads();
    for (int s = 128; s; s >>= 1) { if (tid < s) red[tid] += red[tid + s]; __syncthreads(); }
    if (tid == 0) { scal[b * 8 + 6] = csq; scal[b * 8 + 7] = red[0]; }
  }
}

// ---------------- spread partials: sum_t y*||u-cen|| (wave per row, atomic per block) ---
__global__ __launch_bounds__(256) void k_ydist(const u16* __restrict__ ubf,
                                               const float* __restrict__ uf, int use_ubf,
                                               const float* __restrict__ cnorm,
                                               const float* __restrict__ unorm2,
                                               const float* __restrict__ y,
                                               float* __restrict__ scal) {
  __shared__ float s4[4];
  int wv = threadIdx.x >> 6;
  int wid = blockIdx.x * 4 + wv;
  int lane = threadIdx.x & 63;
  int b = wid >> 11;
  const float4* cr = (const float4*)(cnorm + (size_t)b * cDU);
  float4 cx0 = cr[lane * 2], cx1 = cr[lane * 2 + 1];
  float dot;
  if (use_ubf) {
    u16x8 s = *(const u16x8*)(ubf + (size_t)wid * cDU + lane * 8);
    dot = bf2f(s[0]) * cx0.x + bf2f(s[1]) * cx0.y + bf2f(s[2]) * cx0.z + bf2f(s[3]) * cx0.w +
          bf2f(s[4]) * cx1.x + bf2f(s[5]) * cx1.y + bf2f(s[6]) * cx1.z + bf2f(s[7]) * cx1.w;
  } else {
    const float4* ur = (const float4*)(uf + (size_t)wid * cDU);
    dot = dot4(ur[lane * 2], cx0) + dot4(ur[lane * 2 + 1], cx1);
  }
  dot = wave_sum(dot);
  if (lane == 0) {
    float d2 = unorm2[wid] - 2.f * dot + scal[b * 8 + 7];
    s4[wv] = y[wid] * sqrtf(fmaxf(d2, 0.f));
  }
  __syncthreads();
  if (threadIdx.x == 0)
    atomicAdd(&scal[b * 8 + 4], s4[0] + s4[1] + s4[2] + s4[3]);
}

// ---------------- fused GRU: gates + memory update + output (wave per (b,i)) ----------
__global__ __launch_bounds__(256) void k_gru(const float* __restrict__ z,
                                             const float* __restrict__ scal,
                                             const float* __restrict__ memin,
                                             float* __restrict__ memout,
                                             const float* __restrict__ W_ih,
                                             const float* __restrict__ b_ih,
                                             const float* __restrict__ W_hh,
                                             const float* __restrict__ b_hh,
                                             float* __restrict__ out, int stage) {
  int wid = blockIdx.x * 4 + (threadIdx.x >> 6);
  int lane = threadIdx.x & 63;
  int b = wid >> 9, i = wid & 511;
  const float4* xz = (const float4*)(z + (size_t)b * cDU);
  const float4* xm = (const float4*)(memin + (size_t)b * cDM);
  float4 z0 = xz[lane * 2], z1 = xz[lane * 2 + 1];
  float4 m0 = xm[lane * 2], m1 = xm[lane * 2 + 1];
  float ysc = scal[b * 8 + 0];
  float cov = scal[b * 8 + 1], ent = scal[b * 8 + 2];
  float spr = scal[b * 8 + 4] / ysc;
  float cmp = 2.f * (ysc * scal[b * 8 + 3] - scal[b * 8 + 6]) / fmaxf(ysc * ysc, cEPS);
  float aI[3], aH[3];
#pragma unroll
  for (int g = 0; g < 3; ++g) {
    size_t row = (size_t)(g * 512 + i);
    const float4* wI = (const float4*)(W_ih + row * 516);
    float a = dot4(z0, wI[lane * 2]) + dot4(z1, wI[lane * 2 + 1]);
    if (lane == 0) {
      float4 wt = wI[128];   // elements 512..515 = [coverage, entropy, spread, compact]
      a += cov * wt.x + ent * wt.y + spr * wt.z + cmp * wt.w;
    }
    aI[g] = wave_sum(a);
    const float4* wH = (const float4*)(W_hh + row * cDM);
    float h = dot4(m0, wH[lane * 2]) + dot4(m1, wH[lane * 2 + 1]);
    aH[g] = wave_sum(h);
  }
  if (lane == 0) {
    float gir = aI[0] + b_ih[i],        ghr = aH[0] + b_hh[i];
    float giz = aI[1] + b_ih[512 + i],  ghz = aH[1] + b_hh[512 + i];
    float gin = aI[2] + b_ih[1024 + i], ghn = aH[2] + b_hh[1024 + i];
    float rg = 1.f / (1.f + expf(-(gir + ghr)));
    float zg = 1.f / (1.f + expf(-(giz + ghz)));
    float ng = tanhf(gin + rg * ghn);
    float mold = memin[b * cDM + i];
    memout[b * cDM + i] = (1.f - zg) * ng + zg * mold;
    out[(size_t)(b * cL + stage) * cDU + i] = z[b * cDU + i];
  }
}

extern "C" void kernel_launch(void* const* d_in, const int* in_sizes, int n_in,
                              void* d_out, int out_size, void* d_ws, size_t ws_size,
                              hipStream_t stream) {
  const float* u    = (const float*)d_in[0];
  const float* sf   = (const float*)d_in[1];
  const float* sim  = (const float*)d_in[2];
  const float* mem0 = (const float*)d_in[3];
  const float* Wq   = (const float*)d_in[4];
  const float* Wk   = (const float*)d_in[5];
  const float* Wv   = (const float*)d_in[6];
  const float* sbw1 = (const float*)d_in[7];
  const float* sbb1 = (const float*)d_in[8];
  const float* sbw2 = (const float*)d_in[9];
  const float* sbb2 = (const float*)d_in[10];
  const float* logt = (const float*)d_in[11];
  const float* W_ih = (const float*)d_in[12];
  const float* b_ih = (const float*)d_in[13];
  const float* W_hh = (const float*)d_in[14];
  const float* b_hh = (const float*)d_in[15];
  float* out = (float*)d_out;
  float* ws  = (float*)d_ws;
  u16* ubf   = (u16*)((char*)d_ws + U_OFFB);
  u16* simbf = (u16*)((char*)d_ws + SIM_OFFB);

  const int use_ubf   = (ws_size >= WS_NEED_U) ? 1 : 0;
  const int use_simbf = (ws_size >= WS_NEED_ALL) ? 1 : 0;

  // precompute sbias + unorm2 (fp32 exact)
  k_pre<<<(cB * cT) / 4, 256, 0, stream>>>(sf, u, sbw1, sbb1, sbw2, sbb2,
                                           ws + F_SB, ws + F_UN);
  if (use_ubf)
    k_cast<<<2048, 256, 0, stream>>>(u, sim, ubf, simbf, use_simbf);
  hipMemcpyAsync(ws + F_M0, mem0, (size_t)cB * cDM * sizeof(float),
                 hipMemcpyDeviceToDevice, stream);

  for (int stage = 0; stage < cL; ++stage) {
    float* mcur = ws + ((stage & 1) ? F_M1 : F_M0);
    float* mnxt = ws + ((stage & 1) ? F_M0 : F_M1);
    k_q<<<512, 256, 0, stream>>>(mcur, Wq, ws + F_Q);
    k_qk<<<cB, 512, 0, stream>>>(ws + F_Q, Wk, ws + F_QK);
    k_scores<<<4096, 256, 0, stream>>>(ubf, u, ws + F_QK, ws + F_SB, simbf, sim,
                                       ws + F_PR, logt, stage == 0 ? 0.0f : cGAMMA,
                                       use_ubf, use_simbf, ws + F_LG);
    k_softmax<<<cB, 1024, 0, stream>>>(ws + F_LG, ws + F_Y);
    k_overlap<<<4096, 256, 0, stream>>>(simbf, sim, ws + F_Y, use_simbf, ws + F_OV);
    k_soft2<<<cB, 1024, 0, stream>>>(ws + F_OV, ws + F_LG, ws + F_Y, ws + F_PR,
                                     ws + F_UN, ws + F_SC, ws + F_C, stage == 0 ? 1 : 0);
    k_cen1<<<dim3(32, cB), 256, 0, stream>>>(ws + F_Y, ubf, u, use_ubf, ws + F_C);
    k_zcen<<<1032, 256, 0, stream>>>(ws + F_C, Wv, ws + F_Z, ws + F_CN, ws + F_SC);
    k_ydist<<<4096, 256, 0, stream>>>(ubf, u, use_ubf, ws + F_CN, ws + F_UN,
                                      ws + F_Y, ws + F_SC);
    k_gru<<<1024, 256, 0, stream>>>(ws + F_Z, ws + F_SC, mcur, mnxt,
                                    W_ih, b_ih, W_hh, b_hh, out, stage);
  }
}

// Round 3
// 613.769 us; speedup vs baseline: 1.7932x; 1.7932x over previous
//
#include <hip/hip_runtime.h>
#include <math.h>

constexpr int cB = 8, cT = 2048, cDU = 512, cDM = 512, cDA = 256, cDF = 12, cL = 4;
constexpr float cEPS = 1e-6f;
constexpr float cSCALE = 16.0f;   // sqrt(DA)
constexpr float cGAMMA = 1.0f;

typedef unsigned short u16;
typedef u16 u16x8 __attribute__((ext_vector_type(8)));

// ---------------- workspace layout ----------------
constexpr size_t F_SB = 0;                 // sbias  B*T
constexpr size_t F_UN = F_SB + 16384;      // unorm2 B*T
constexpr size_t F_LG = F_UN + 16384;      // logits B*T
constexpr size_t F_Y  = F_LG + 16384;      // y      B*T
constexpr size_t F_PR = F_Y  + 16384;      // prev   B*T
constexpr size_t F_OV = F_PR + 16384;      // overlap B*T
constexpr size_t F_SP = F_OV + 16384;      // spread partials B*32 (reuses old q slot)
constexpr size_t F_QK = F_SP + 2048;       // qk  B*DU
constexpr size_t F_M0 = F_QK + 4096;       // memory buf 0
constexpr size_t F_M1 = F_M0 + 4096;       // memory buf 1
constexpr size_t F_C  = F_M1 + 4096;       // c_raw B*DU
constexpr size_t F_CN = F_C  + 4096;       // cnorm B*DU
constexpr size_t F_Z  = F_CN + 4096;       // z B*DU
constexpr size_t F_SC = F_Z  + 4096;       // scalars B*8
constexpr size_t F_END = F_SC + 64;
constexpr size_t U_OFFB   = F_END * 4;
constexpr size_t U_BYTES  = (size_t)cB * cT * cDU * 2;
constexpr size_t SIM_OFFB = U_OFFB + U_BYTES;
constexpr size_t SIM_BYTES= (size_t)cB * cT * cT * 2;
constexpr size_t WS_NEED_U   = U_OFFB + U_BYTES;
constexpr size_t WS_NEED_ALL = SIM_OFFB + SIM_BYTES;
// scal: 0 ysum_clamped, 1 coverage, 2 entropy, 3 wsq, 6 csq, 7 cen2

__device__ __forceinline__ float wave_sum(float v) {
#pragma unroll
  for (int o = 32; o; o >>= 1) v += __shfl_down(v, o);
  return v;
}
__device__ __forceinline__ float block_reduce_sum(float v, float* red) {
  int tid = threadIdx.x;
  red[tid] = v; __syncthreads();
  for (int s = 512; s; s >>= 1) { if (tid < s) red[tid] += red[tid + s]; __syncthreads(); }
  float r = red[0]; __syncthreads();
  return r;
}
__device__ __forceinline__ float block_reduce_max(float v, float* red) {
  int tid = threadIdx.x;
  red[tid] = v; __syncthreads();
  for (int s = 512; s; s >>= 1) { if (tid < s) red[tid] = fmaxf(red[tid], red[tid + s]); __syncthreads(); }
  float r = red[0]; __syncthreads();
  return r;
}
__device__ __forceinline__ u16 f2bf(float f) {
  unsigned u = __float_as_uint(f);
  unsigned r = (u + 0x7fffu + ((u >> 16) & 1u)) >> 16;
  return (u16)r;
}
__device__ __forceinline__ float bf2f(u16 h) { return __uint_as_float(((unsigned)h) << 16); }
__device__ __forceinline__ float dot4(float4 a, float4 b) {
  return a.x * b.x + a.y * b.y + a.z * b.z + a.w * b.w;
}

// ---------------- cast u (+ sim) to bf16 ----------------
__global__ void k_cast(const float* __restrict__ u, const float* __restrict__ sim,
                       u16* __restrict__ ubf, u16* __restrict__ simbf, int do_sim) {
  const int NU8 = (cB * cT * cDU) / 8;
  const int NS8 = (cB * cT * cT) / 8;
  int total = do_sim ? (NU8 + NS8) : NU8;
  for (int idx = blockIdx.x * blockDim.x + threadIdx.x; idx < total;
       idx += gridDim.x * blockDim.x) {
    const float4* src; u16* dst; size_t c;
    if (idx < NU8) { src = (const float4*)u; dst = ubf; c = idx; }
    else           { src = (const float4*)sim; dst = simbf; c = idx - NU8; }
    float4 f0 = src[c * 2], f1 = src[c * 2 + 1];
    u16x8 o;
    o[0] = f2bf(f0.x); o[1] = f2bf(f0.y); o[2] = f2bf(f0.z); o[3] = f2bf(f0.w);
    o[4] = f2bf(f1.x); o[5] = f2bf(f1.y); o[6] = f2bf(f1.z); o[7] = f2bf(f1.w);
    *(u16x8*)(dst + c * 8) = o;
  }
}

// ---------------- precompute: sbias + unorm2 (one wave per (b,t)) ----------------
__global__ void k_pre(const float* __restrict__ sf, const float* __restrict__ u,
                      const float* __restrict__ w1, const float* __restrict__ b1,
                      const float* __restrict__ w2, const float* __restrict__ b2,
                      float* __restrict__ sbias, float* __restrict__ unorm2) {
  int wid = (blockIdx.x * blockDim.x + threadIdx.x) >> 6;
  int lane = threadIdx.x & 63;
  float d0 = sf[(size_t)wid * cDF + 8];
  float d1 = sf[(size_t)wid * cDF + 9];
  float d2 = sf[(size_t)wid * cDF + 10];
  float acc = 0.f;
#pragma unroll
  for (int i = 0; i < 4; ++i) {
    int a = lane * 4 + i;
    float h = d0 * w1[a * 3 + 0] + d1 * w1[a * 3 + 1] + d2 * w1[a * 3 + 2] + b1[a];
    float g = 0.5f * h * (1.0f + erff(h * 0.70710678118654752f));
    acc += g * w2[a];
  }
  float un = 0.f;
  const float4* ur = (const float4*)(u + (size_t)wid * cDU);
#pragma unroll
  for (int m = 0; m < 2; ++m) {
    float4 x = ur[lane + m * 64];
    un += dot4(x, x);
  }
  acc = wave_sum(acc);
  un = wave_sum(un);
  if (lane == 0) { sbias[wid] = acc + b2[0]; unorm2[wid] = un; }
}

// ---------------- fused q = mem@Wq^T then qk = Wk^T@q (block per b) ----------------
__global__ __launch_bounds__(1024) void k_qqk(const float* __restrict__ mem,
                                              const float* __restrict__ Wq,
                                              const float* __restrict__ Wk,
                                              float* __restrict__ qk) {
  __shared__ float qs[cDA];
  __shared__ float red2[1024];
  int b = blockIdx.x, tid = threadIdx.x;
  int wv = tid >> 6, lane = tid & 63;
  const float4* mr = (const float4*)(mem + (size_t)b * cDM);
  float4 m0 = mr[lane * 2], m1 = mr[lane * 2 + 1];
#pragma unroll
  for (int ii = 0; ii < 16; ++ii) {
    int a = wv * 16 + ii;
    const float4* wr = (const float4*)(Wq + (size_t)a * cDM);
    float acc = dot4(m0, wr[lane * 2]) + dot4(m1, wr[lane * 2 + 1]);
    acc = wave_sum(acc);
    if (lane == 0) qs[a] = acc;
  }
  __syncthreads();
  int j = tid & 511;
  int half = tid >> 9;
  float acc = 0.f;
#pragma unroll 4
  for (int a = half * 128; a < half * 128 + 128; ++a)
    acc += Wk[(size_t)a * cDU + j] * qs[a];
  red2[tid] = acc;
  __syncthreads();
  if (tid < 512) qk[b * cDU + j] = red2[tid] + red2[tid + 512];
}

// ---------------- logits = (u.qk/SCALE + sbias - gamma*sim@prev)/temp ----------------
__global__ void k_scores(const u16* __restrict__ ubf, const float* __restrict__ uf,
                         const float* __restrict__ qk, const float* __restrict__ sbias,
                         const u16* __restrict__ simbf, const float* __restrict__ simf,
                         const float* __restrict__ prev, const float* __restrict__ log_temp,
                         float gamma, int use_ubf, int use_simbf,
                         float* __restrict__ logits) {
  int wid = (blockIdx.x * blockDim.x + threadIdx.x) >> 6;
  int lane = threadIdx.x & 63;
  int b = wid >> 11;
  const float4* qk4 = (const float4*)(qk + (size_t)b * cDU);
  float4 q0 = qk4[lane * 2], q1 = qk4[lane * 2 + 1];
  float acc;
  if (use_ubf) {
    u16x8 s = *(const u16x8*)(ubf + (size_t)wid * cDU + lane * 8);
    acc = bf2f(s[0]) * q0.x + bf2f(s[1]) * q0.y + bf2f(s[2]) * q0.z + bf2f(s[3]) * q0.w +
          bf2f(s[4]) * q1.x + bf2f(s[5]) * q1.y + bf2f(s[6]) * q1.z + bf2f(s[7]) * q1.w;
  } else {
    const float4* ur = (const float4*)(uf + (size_t)wid * cDU);
    acc = dot4(ur[lane * 2], q0) + dot4(ur[lane * 2 + 1], q1);
  }
  acc *= (1.0f / cSCALE);
  if (gamma != 0.0f) {
    float sd = 0.f;
    const float4* pr4 = (const float4*)(prev + (size_t)b * cT);
    if (use_simbf) {
#pragma unroll
      for (int m = 0; m < 4; ++m) {
        u16x8 s = *(const u16x8*)(simbf + (size_t)wid * cT + m * 512 + lane * 8);
        float4 p0 = pr4[m * 128 + lane * 2], p1 = pr4[m * 128 + lane * 2 + 1];
        sd += bf2f(s[0]) * p0.x + bf2f(s[1]) * p0.y + bf2f(s[2]) * p0.z + bf2f(s[3]) * p0.w +
              bf2f(s[4]) * p1.x + bf2f(s[5]) * p1.y + bf2f(s[6]) * p1.z + bf2f(s[7]) * p1.w;
      }
    } else {
      const float4* sr = (const float4*)(simf + (size_t)wid * cT);
#pragma unroll
      for (int m = 0; m < 8; ++m) sd += dot4(sr[lane + m * 64], pr4[lane + m * 64]);
    }
    acc -= gamma * sd;
  }
  acc = wave_sum(acc);
  if (lane == 0) {
    float temp = fminf(fmaxf(expf(log_temp[0]), 0.1f), 10.0f);
    logits[wid] = (acc + sbias[wid]) / temp;
  }
}

// ---------------- softmax over T per b ----------------
__global__ __launch_bounds__(1024) void k_softmax(const float* __restrict__ logits,
                                                  float* __restrict__ y) {
  __shared__ float red[1024];
  int b = blockIdx.x, tid = threadIdx.x;
  int i0 = b * cT + tid, i1 = i0 + 1024;
  float l0 = logits[i0], l1 = logits[i1];
  float m = block_reduce_max(fmaxf(l0, l1), red);
  float e0 = expf(l0 - m), e1 = expf(l1 - m);
  float S = block_reduce_sum(e0 + e1, red);
  y[i0] = e0 / S; y[i1] = e1 / S;
}

// ---------------- overlap = sim @ y ----------------
__global__ void k_overlap(const u16* __restrict__ simbf, const float* __restrict__ simf,
                          const float* __restrict__ y, int use_simbf,
                          float* __restrict__ overlap) {
  int wid = (blockIdx.x * blockDim.x + threadIdx.x) >> 6;
  int lane = threadIdx.x & 63;
  int b = wid >> 11;
  const float4* yr4 = (const float4*)(y + (size_t)b * cT);
  float acc = 0.f;
  if (use_simbf) {
#pragma unroll
    for (int m = 0; m < 4; ++m) {
      u16x8 s = *(const u16x8*)(simbf + (size_t)wid * cT + m * 512 + lane * 8);
      float4 p0 = yr4[m * 128 + lane * 2], p1 = yr4[m * 128 + lane * 2 + 1];
      acc += bf2f(s[0]) * p0.x + bf2f(s[1]) * p0.y + bf2f(s[2]) * p0.z + bf2f(s[3]) * p0.w +
             bf2f(s[4]) * p1.x + bf2f(s[5]) * p1.y + bf2f(s[6]) * p1.z + bf2f(s[7]) * p1.w;
    }
  } else {
    const float4* sr = (const float4*)(simf + (size_t)wid * cT);
#pragma unroll
    for (int m = 0; m < 8; ++m) acc += dot4(sr[lane + m * 64], yr4[lane + m * 64]);
  }
  acc = wave_sum(acc);
  if (lane == 0) overlap[wid] = acc;
}

// ---------------- penalty + softmax#2 + prev + coverage/entropy/wsq ----------------
__global__ __launch_bounds__(1024) void k_soft2(const float* __restrict__ overlap,
                                                const float* __restrict__ logits,
                                                float* __restrict__ y, float* __restrict__ prev,
                                                const float* __restrict__ unorm2,
                                                float* __restrict__ scal,
                                                float* __restrict__ c_raw, int first_stage) {
  __shared__ float red[1024];
  int b = blockIdx.x, tid = threadIdx.x;
  int i0 = b * cT + tid, i1 = i0 + 1024;
  float o0 = overlap[i0], o1 = overlap[i1];
  float mo = fmaxf(block_reduce_max(fmaxf(o0, o1), red), cEPS);
  float l0 = logits[i0] - o0 / mo;
  float l1 = logits[i1] - o1 / mo;
  float ml = block_reduce_max(fmaxf(l0, l1), red);
  float e0 = expf(l0 - ml), e1 = expf(l1 - ml);
  float S = block_reduce_sum(e0 + e1, red);
  float y0 = e0 / S, y1 = e1 / S;
  y[i0] = y0; y[i1] = y1;
  if (first_stage) { prev[i0] = y0; prev[i1] = y1; }
  else             { prev[i0] += y0; prev[i1] += y1; }
  if (tid < cDU) c_raw[b * cDU + tid] = 0.f;
  float ysr = block_reduce_sum(y0 + y1, red);
  float ysc = fmaxf(ysr, cEPS);
  float wsq = block_reduce_sum(y0 * unorm2[i0] + y1 * unorm2[i1], red);
  float yn0 = y0 / ysc, yn1 = y1 / ysc;
  float ent = block_reduce_sum(-yn0 * logf(fmaxf(yn0, cEPS)) - yn1 * logf(fmaxf(yn1, cEPS)), red);
  if (tid == 0) {
    scal[b * 8 + 0] = ysc;
    scal[b * 8 + 1] = ysr / (float)cT;
    scal[b * 8 + 2] = ent;
    scal[b * 8 + 3] = wsq;
  }
}

// ---------------- centroid partials: c_raw += y @ u (vectorized, LDS-combined) --------
__global__ __launch_bounds__(256) void k_cen1(const float* __restrict__ y,
                                              const u16* __restrict__ ubf,
                                              const float* __restrict__ uf, int use_ubf,
                                              float* __restrict__ c_raw) {
  __shared__ float lds[4][512];
  int b = blockIdx.y, tc = blockIdx.x;
  int wv = threadIdx.x >> 6, lane = threadIdx.x & 63;
  float acc[8] = {};
  for (int i = 0; i < 16; ++i) {
    int row = b * cT + tc * 64 + wv * 16 + i;
    float yv = y[row];
    if (use_ubf) {
      u16x8 s = *(const u16x8*)(ubf + (size_t)row * cDU + lane * 8);
#pragma unroll
      for (int e = 0; e < 8; ++e) acc[e] += yv * bf2f(s[e]);
    } else {
      const float4* ur = (const float4*)(uf + (size_t)row * cDU);
      float4 a0 = ur[lane * 2], a1 = ur[lane * 2 + 1];
      acc[0] += yv * a0.x; acc[1] += yv * a0.y; acc[2] += yv * a0.z; acc[3] += yv * a0.w;
      acc[4] += yv * a1.x; acc[5] += yv * a1.y; acc[6] += yv * a1.z; acc[7] += yv * a1.w;
    }
  }
#pragma unroll
  for (int e = 0; e < 8; ++e) lds[wv][lane * 8 + e] = acc[e];
  __syncthreads();
  int d0 = threadIdx.x, d1 = threadIdx.x + 256;
  float s0 = lds[0][d0] + lds[1][d0] + lds[2][d0] + lds[3][d0];
  float s1 = lds[0][d1] + lds[1][d1] + lds[2][d1] + lds[3][d1];
  atomicAdd(&c_raw[b * cDU + d0], s0);
  atomicAdd(&c_raw[b * cDU + d1], s1);
}

// ---------------- fused: z = c_raw @ Wv^T  +  centroid finalize ----------------
__global__ __launch_bounds__(256) void k_zcen(const float* __restrict__ c_raw,
                                              const float* __restrict__ Wv,
                                              float* __restrict__ z,
                                              float* __restrict__ cnorm,
                                              float* __restrict__ scal) {
  if (blockIdx.x < 1024) {
    int wid = blockIdx.x * 4 + (threadIdx.x >> 6);
    int lane = threadIdx.x & 63;
    int b = wid >> 9, j = wid & 511;
    const float4* c4 = (const float4*)(c_raw + (size_t)b * cDU);
    const float4* w4 = (const float4*)(Wv + (size_t)j * cDU);
    float acc = dot4(c4[lane * 2], w4[lane * 2]) + dot4(c4[lane * 2 + 1], w4[lane * 2 + 1]);
    acc = wave_sum(acc);
    if (lane == 0) z[b * cDU + j] = acc;
  } else {
    __shared__ float red[256];
    int b = blockIdx.x - 1024, tid = threadIdx.x;
    float ysc = scal[b * 8 + 0];
    float c0 = c_raw[b * cDU + tid], c1 = c_raw[b * cDU + tid + 256];
    float n0 = c0 / ysc, n1 = c1 / ysc;
    cnorm[b * cDU + tid] = n0; cnorm[b * cDU + tid + 256] = n1;
    red[tid] = c0 * c0 + c1 * c1; __syncthreads();
    for (int s = 128; s; s >>= 1) { if (tid < s) red[tid] += red[tid + s]; __syncthreads(); }
    float csq = red[0]; __syncthreads();
    red[tid] = n0 * n0 + n1 * n1; __syncthreads();
    for (int s = 128; s; s >>= 1) { if (tid < s) red[tid] += red[tid + s]; __syncthreads(); }
    if (tid == 0) { scal[b * 8 + 6] = csq; scal[b * 8 + 7] = red[0]; }
  }
}

// ---------------- spread partials (NO atomics): sprp[b*32+tc] = sum_chunk y*||u-cen|| ---
__global__ __launch_bounds__(256) void k_ydist(const u16* __restrict__ ubf,
                                               const float* __restrict__ uf, int use_ubf,
                                               const float* __restrict__ cnorm,
                                               const float* __restrict__ unorm2,
                                               const float* __restrict__ y,
                                               const float* __restrict__ scal,
                                               float* __restrict__ sprp) {
  __shared__ float s4[4];
  int b = blockIdx.y, tc = blockIdx.x;
  int wv = threadIdx.x >> 6, lane = threadIdx.x & 63;
  const float4* cr = (const float4*)(cnorm + (size_t)b * cDU);
  float4 cx0 = cr[lane * 2], cx1 = cr[lane * 2 + 1];
  float cen2 = scal[b * 8 + 7];
  float part = 0.f;
  for (int i = 0; i < 16; ++i) {
    int row = b * cT + tc * 64 + wv * 16 + i;
    float dot;
    if (use_ubf) {
      u16x8 s = *(const u16x8*)(ubf + (size_t)row * cDU + lane * 8);
      dot = bf2f(s[0]) * cx0.x + bf2f(s[1]) * cx0.y + bf2f(s[2]) * cx0.z + bf2f(s[3]) * cx0.w +
            bf2f(s[4]) * cx1.x + bf2f(s[5]) * cx1.y + bf2f(s[6]) * cx1.z + bf2f(s[7]) * cx1.w;
    } else {
      const float4* ur = (const float4*)(uf + (size_t)row * cDU);
      dot = dot4(ur[lane * 2], cx0) + dot4(ur[lane * 2 + 1], cx1);
    }
    dot = wave_sum(dot);
    if (lane == 0) {
      float d2 = unorm2[row] - 2.f * dot + cen2;
      part += y[row] * sqrtf(fmaxf(d2, 0.f));
    }
  }
  if (lane == 0) s4[wv] = part;
  __syncthreads();
  if (threadIdx.x == 0) sprp[b * 32 + tc] = s4[0] + s4[1] + s4[2] + s4[3];
}

// ---------------- fused GRU (also folds spread-partial reduction) ----------------
__global__ __launch_bounds__(256) void k_gru(const float* __restrict__ z,
                                             const float* __restrict__ scal,
                                             const float* __restrict__ sprp,
                                             const float* __restrict__ memin,
                                             float* __restrict__ memout,
                                             const float* __restrict__ W_ih,
                                             const float* __restrict__ b_ih,
                                             const float* __restrict__ W_hh,
                                             const float* __restrict__ b_hh,
                                             float* __restrict__ out, int stage) {
  int wid = blockIdx.x * 4 + (threadIdx.x >> 6);
  int lane = threadIdx.x & 63;
  int b = wid >> 9, i = wid & 511;
  const float4* xz = (const float4*)(z + (size_t)b * cDU);
  const float4* xm = (const float4*)(memin + (size_t)b * cDM);
  float4 z0 = xz[lane * 2], z1 = xz[lane * 2 + 1];
  float4 m0 = xm[lane * 2], m1 = xm[lane * 2 + 1];
  float ysc = scal[b * 8 + 0];
  float cov = scal[b * 8 + 1], ent = scal[b * 8 + 2];
  float spr_raw = 0.f;
#pragma unroll
  for (int t = 0; t < 32; ++t) spr_raw += sprp[b * 32 + t];
  float spr = spr_raw / ysc;
  float cmp = 2.f * (ysc * scal[b * 8 + 3] - scal[b * 8 + 6]) / fmaxf(ysc * ysc, cEPS);
  float aI[3], aH[3];
#pragma unroll
  for (int g = 0; g < 3; ++g) {
    size_t row = (size_t)(g * 512 + i);
    const float4* wI = (const float4*)(W_ih + row * 516);
    float a = dot4(z0, wI[lane * 2]) + dot4(z1, wI[lane * 2 + 1]);
    if (lane == 0) {
      float4 wt = wI[128];
      a += cov * wt.x + ent * wt.y + spr * wt.z + cmp * wt.w;
    }
    aI[g] = wave_sum(a);
    const float4* wH = (const float4*)(W_hh + row * cDM);
    float h = dot4(m0, wH[lane * 2]) + dot4(m1, wH[lane * 2 + 1]);
    aH[g] = wave_sum(h);
  }
  if (lane == 0) {
    float gir = aI[0] + b_ih[i],        ghr = aH[0] + b_hh[i];
    float giz = aI[1] + b_ih[512 + i],  ghz = aH[1] + b_hh[512 + i];
    float gin = aI[2] + b_ih[1024 + i], ghn = aH[2] + b_hh[1024 + i];
    float rg = 1.f / (1.f + expf(-(gir + ghr)));
    float zg = 1.f / (1.f + expf(-(giz + ghz)));
    float ng = tanhf(gin + rg * ghn);
    float mold = memin[b * cDM + i];
    memout[b * cDM + i] = (1.f - zg) * ng + zg * mold;
    out[(size_t)(b * cL + stage) * cDU + i] = z[b * cDU + i];
  }
}

extern "C" void kernel_launch(void* const* d_in, const int* in_sizes, int n_in,
                              void* d_out, int out_size, void* d_ws, size_t ws_size,
                              hipStream_t stream) {
  const float* u    = (const float*)d_in[0];
  const float* sf   = (const float*)d_in[1];
  const float* sim  = (const float*)d_in[2];
  const float* mem0 = (const float*)d_in[3];
  const float* Wq   = (const float*)d_in[4];
  const float* Wk   = (const float*)d_in[5];
  const float* Wv   = (const float*)d_in[6];
  const float* sbw1 = (const float*)d_in[7];
  const float* sbb1 = (const float*)d_in[8];
  const float* sbw2 = (const float*)d_in[9];
  const float* sbb2 = (const float*)d_in[10];
  const float* logt = (const float*)d_in[11];
  const float* W_ih = (const float*)d_in[12];
  const float* b_ih = (const float*)d_in[13];
  const float* W_hh = (const float*)d_in[14];
  const float* b_hh = (const float*)d_in[15];
  float* out = (float*)d_out;
  float* ws  = (float*)d_ws;
  u16* ubf   = (u16*)((char*)d_ws + U_OFFB);
  u16* simbf = (u16*)((char*)d_ws + SIM_OFFB);

  const int use_ubf   = (ws_size >= WS_NEED_U) ? 1 : 0;
  const int use_simbf = (ws_size >= WS_NEED_ALL) ? 1 : 0;

  k_pre<<<(cB * cT) / 4, 256, 0, stream>>>(sf, u, sbw1, sbb1, sbw2, sbb2,
                                           ws + F_SB, ws + F_UN);
  if (use_ubf)
    k_cast<<<2048, 256, 0, stream>>>(u, sim, ubf, simbf, use_simbf);
  hipMemcpyAsync(ws + F_M0, mem0, (size_t)cB * cDM * sizeof(float),
                 hipMemcpyDeviceToDevice, stream);

  for (int stage = 0; stage < cL; ++stage) {
    float* mcur = ws + ((stage & 1) ? F_M1 : F_M0);
    float* mnxt = ws + ((stage & 1) ? F_M0 : F_M1);
    k_qqk<<<cB, 1024, 0, stream>>>(mcur, Wq, Wk, ws + F_QK);
    k_scores<<<4096, 256, 0, stream>>>(ubf, u, ws + F_QK, ws + F_SB, simbf, sim,
                                       ws + F_PR, logt, stage == 0 ? 0.0f : cGAMMA,
                                       use_ubf, use_simbf, ws + F_LG);
    k_softmax<<<cB, 1024, 0, stream>>>(ws + F_LG, ws + F_Y);
    k_overlap<<<4096, 256, 0, stream>>>(simbf, sim, ws + F_Y, use_simbf, ws + F_OV);
    k_soft2<<<cB, 1024, 0, stream>>>(ws + F_OV, ws + F_LG, ws + F_Y, ws + F_PR,
                                     ws + F_UN, ws + F_SC, ws + F_C, stage == 0 ? 1 : 0);
    k_cen1<<<dim3(32, cB), 256, 0, stream>>>(ws + F_Y, ubf, u, use_ubf, ws + F_C);
    k_zcen<<<1032, 256, 0, stream>>>(ws + F_C, Wv, ws + F_Z, ws + F_CN, ws + F_SC);
    k_ydist<<<dim3(32, cB), 256, 0, stream>>>(ubf, u, use_ubf, ws + F_CN, ws + F_UN,
                                              ws + F_Y, ws + F_SC, ws + F_SP);
    k_gru<<<1024, 256, 0, stream>>>(ws + F_Z, ws + F_SC, ws + F_SP, mcur, mnxt,
                                    W_ih, b_ih, W_hh, b_hh, out, stage);
  }
}